// Round 9
// baseline (71.486 us; speedup 1.0000x reference)
//
#include <hip/hip_runtime.h>
#include <cstdint>
#include <cstddef>

#define EPSV 1e-5f
typedef uint32_t u32;
typedef unsigned short u16;
typedef __attribute__((ext_vector_type(8))) short bf16x8;
typedef __attribute__((ext_vector_type(4))) float f32x4;

__device__ __forceinline__ u16 f2b(float x){ union { float f; u32 i; } v; v.f=x; u32 t=v.i; return (u16)((t + 0x7fffu + ((t>>16)&1u))>>16); }

// ---------------- stage A (MFMA): conv1x1(q,k) + BN + ReLU + spatial partial-sum ----------------
// grid: 1664 blocks = 128 n x 13 tile-groups; 256 threads = 4 waves, wave = one 16-px tile.
// 784 = 49*16 exactly; tiles 49..51 idle. W fold+swizzle done in-block (no prep kernel):
// frag-slot f=(kk*4+nt)*64+lane holds 8 bf16: c = kk*32+(lane>>4)*8+j, o = nt*16+(lane&15).
__global__ __launch_bounds__(256) void k_stageA(
    const float* __restrict__ x,
    const float* __restrict__ wq, const float* __restrict__ bq, const float* __restrict__ gq,
    const float* __restrict__ betaq, const float* __restrict__ mq, const float* __restrict__ vq,
    const float* __restrict__ wk, const float* __restrict__ bk, const float* __restrict__ gk,
    const float* __restrict__ betak, const float* __restrict__ mk, const float* __restrict__ vk,
    float* __restrict__ qk_part)
{
  __shared__ __align__(16) u16 Wl[16384];   // 32 KB of B-fragments
  __shared__ float Dsh[64];
  const int tid = threadIdx.x;
  const int n = blockIdx.x / 13, g = blockIdx.x % 13;
  const int wv = tid >> 6, lane = tid & 63;
  const int tile = g*4 + wv;
  const bool active = (tile < 49);

  // ---- early-issue first x prefetch (hides under the W fold) ----
  const int px = tile*16 + (lane & 15);
  const float* xr = x + (size_t)n*200704 + px;
  const int krow = (lane >> 4) * 8;           // k-offset within the 32-wide K step
  float a[8];
  if (active) {
#pragma unroll
    for (int j = 0; j < 8; ++j) a[j] = xr[(size_t)(krow + j)*784];
  }

  // ---- fold BN scale into W, convert bf16, write swizzled frags to LDS ----
#pragma unroll
  for (int k8 = 0; k8 < 8; ++k8) {
    const int f = tid + k8*256;               // frag-slot 0..2047
    const int fl = f & 63, nt = (f >> 6) & 3, kk = f >> 8;
    const int c0 = kk*32 + ((fl >> 4) << 3);
    const int o = nt*16 + (fl & 15);
    const float* wrow; float gg, vv;
    if (o < 32) { wrow = wq + o*256 + c0;      gg = gq[o];    vv = vq[o]; }
    else        { wrow = wk + (o-32)*256 + c0; gg = gk[o-32]; vv = vk[o-32]; }
    const float s = gg * rsqrtf(vv + EPSV);
    u32 p[4];
#pragma unroll
    for (int h = 0; h < 4; ++h) {
      const u32 lo = f2b(wrow[2*h] * s);
      const u32 hi = f2b(wrow[2*h+1] * s);
      p[h] = lo | (hi << 16);
    }
    uint4 pk; pk.x = p[0]; pk.y = p[1]; pk.z = p[2]; pk.w = p[3];
    reinterpret_cast<uint4*>(Wl)[f] = pk;
  }
  if (tid < 64) {
    const int o = tid;
    float gg,b,be,m,vv;
    if (o < 32) { gg=gq[o];    b=bq[o];    be=betaq[o];    m=mq[o];    vv=vq[o]; }
    else        { gg=gk[o-32]; b=bk[o-32]; be=betak[o-32]; m=mk[o-32]; vv=vk[o-32]; }
    const float s = gg * rsqrtf(vv + EPSV);
    Dsh[o] = (b - m)*s + be;
  }
  __syncthreads();

  float s4[4] = {0.f, 0.f, 0.f, 0.f};
  if (active) {
    const bf16x8* Wf = (const bf16x8*)Wl;
    f32x4 acc[4];
#pragma unroll
    for (int nt = 0; nt < 4; ++nt) acc[nt] = (f32x4){0.f, 0.f, 0.f, 0.f};

    float an[8];
#pragma unroll
    for (int kk = 0; kk < 8; ++kk) {
      if (kk < 7) {
#pragma unroll
        for (int j = 0; j < 8; ++j) an[j] = xr[(size_t)((kk+1)*32 + krow + j)*784];
      }
      bf16x8 af;
#pragma unroll
      for (int j = 0; j < 8; ++j) af[j] = (short)f2b(a[j]);
#pragma unroll
      for (int nt = 0; nt < 4; ++nt) {
        const bf16x8 bf = Wf[(kk*4 + nt)*64 + lane];
        acc[nt] = __builtin_amdgcn_mfma_f32_16x16x32_bf16(af, bf, acc[nt], 0, 0, 0);
      }
#pragma unroll
      for (int j = 0; j < 8; ++j) a[j] = an[j];
    }

    // epilogue: +D, ReLU, sum over the tile's 16 px
    // C layout: o = nt*16 + (lane&15), px-row = (lane>>4)*4 + r
#pragma unroll
    for (int nt = 0; nt < 4; ++nt) {
      const float d = Dsh[nt*16 + (lane & 15)];
      float s = 0.f;
#pragma unroll
      for (int r = 0; r < 4; ++r) s += fmaxf(acc[nt][r] + d, 0.f);
      s += __shfl_down(s, 16, 64);
      s += __shfl_down(s, 32, 64);
      s4[nt] = s;                               // valid on lanes 0..15
    }
  }

  __syncthreads();                              // Wl reads done -> reuse as reduce buffer
  float* red = reinterpret_cast<float*>(Wl);    // need 256 floats
  if (lane < 16) {
#pragma unroll
    for (int nt = 0; nt < 4; ++nt)
      red[wv*64 + nt*16 + lane] = active ? s4[nt] : 0.f;
  }
  __syncthreads();
  if (tid < 64) {
    qk_part[(size_t)(n*13 + g)*64 + tid] =
        red[tid] + red[64+tid] + red[128+tid] + red[192+tid];
  }
}

// ---------------- stage B: per-group 8x8 attention + conv_inflate + BN + ReLU + sigmoid ----------------
__global__ __launch_bounds__(256) void k_stageB(
    const float* __restrict__ qk_part,
    const float* __restrict__ wi, const float* __restrict__ bi, const float* __restrict__ gi,
    const float* __restrict__ betai, const float* __restrict__ mi, const float* __restrict__ vi,
    float* __restrict__ gate)
{
  __shared__ float ql[8][32], vl[8][32], attl[8][8], qul[8][32];
  const int tid = threadIdx.x;
  const int b = blockIdx.x;

  { // gather the 13 tile-group sums, convert to means
    const int i = tid >> 5, c = tid & 31;
    const int n = b*8 + i;
    float sq = 0.f, sv = 0.f;
#pragma unroll
    for (int qq = 0; qq < 13; ++qq) {
      sq += qk_part[(size_t)(n*13 + qq)*64 + c];
      sv += qk_part[(size_t)(n*13 + qq)*64 + 32 + c];
    }
    ql[i][c] = sq * (1.f/784.f);
    vl[i][c] = sv * (1.f/784.f);
  }
  __syncthreads();

  if (tid < 64) { // att[i][j] = -q_i.q_j ; softmax over i (axis 1) for fixed j
    const int i = tid >> 3, j = tid & 7;
    float d = 0.f;
#pragma unroll
    for (int c = 0; c < 32; ++c) d += ql[i][c]*ql[j][c];
    float a = -d;
    float m = a;                        // reduce over i: tid bits 3..5
    m = fmaxf(m, __shfl_xor(m, 8, 64));
    m = fmaxf(m, __shfl_xor(m, 16, 64));
    m = fmaxf(m, __shfl_xor(m, 32, 64));
    const float e = __expf(a - m);
    float s = e;
    s += __shfl_xor(s, 8, 64);
    s += __shfl_xor(s, 16, 64);
    s += __shfl_xor(s, 32, 64);
    attl[i][j] = e / s;
  }
  __syncthreads();

  { // q_upd[i][c] = sum_j att[i][j]*v[j][c] + v[i][c]
    const int i = tid >> 5, c = tid & 31;
    float acc = vl[i][c];
#pragma unroll
    for (int j = 0; j < 8; ++j) acc = fmaf(attl[i][j], vl[j][c], acc);
    qul[i][c] = acc;
  }
  __syncthreads();

  { // y[n,cout] = q_upd . wi[cout,:] (+bi), BN, ReLU, sigmoid
    const int cout = tid;
    float w[32];
#pragma unroll
    for (int k = 0; k < 32; ++k) w[k] = wi[cout*32 + k];
    const float s  = gi[cout] * rsqrtf(vi[cout] + EPSV);
    const float dd = (bi[cout] - mi[cout]) * s + betai[cout];
#pragma unroll
    for (int i = 0; i < 8; ++i) {
      float y = 0.f;
#pragma unroll
      for (int k = 0; k < 32; ++k) y = fmaf(qul[i][k], w[k], y);
      const float t = fmaxf(fmaf(y, s, dd), 0.f);
      gate[(size_t)(b*8 + i)*256 + cout] = 1.f / (1.f + __expf(-t));
    }
  }
}

// ---------------- stage C: out = gate[n,c] * x (non-temporal out stream) ----------------
__global__ __launch_bounds__(256) void k_gateMul(
    const float* __restrict__ x, const float* __restrict__ gate, float* __restrict__ out)
{
  const u32 nchunk = 128u*256u*196u;   // 6,422,528 f32x4 chunks; 196 per (n,c) row
  const u32 stride = gridDim.x * 256u;
  for (u32 q = blockIdx.x*256u + threadIdx.x; q < nchunk; q += stride) {
    const u32 cn = q / 196u;           // n*256 + c
    const float g = gate[cn];
    const f32x4 v = reinterpret_cast<const f32x4*>(x)[q];
    const f32x4 o4 = v * g;
    __builtin_nontemporal_store(o4, reinterpret_cast<f32x4*>(out) + q);
  }
}

extern "C" void kernel_launch(void* const* d_in, const int* in_sizes, int n_in,
                              void* d_out, int out_size, void* d_ws, size_t ws_size,
                              hipStream_t stream) {
  const float* x    = (const float*)d_in[0];
  const float* wq   = (const float*)d_in[1];
  const float* bq   = (const float*)d_in[2];
  const float* gq   = (const float*)d_in[3];
  const float* betaq= (const float*)d_in[4];
  const float* mq   = (const float*)d_in[5];
  const float* vq   = (const float*)d_in[6];
  const float* wk   = (const float*)d_in[7];
  const float* bk   = (const float*)d_in[8];
  const float* gk   = (const float*)d_in[9];
  const float* betak= (const float*)d_in[10];
  const float* mk   = (const float*)d_in[11];
  const float* vk   = (const float*)d_in[12];
  const float* wi   = (const float*)d_in[13];
  const float* bi   = (const float*)d_in[14];
  const float* gi   = (const float*)d_in[15];
  const float* betai= (const float*)d_in[16];
  const float* mi   = (const float*)d_in[17];
  const float* vi   = (const float*)d_in[18];

  char* ws = (char*)d_ws;
  float* qk_part = (float*)(ws);                     // 128*13*64*4 = 425984 B
  float* gate    = (float*)(ws + 425984);            // 128*256*4   = 131072 B

  k_stageA<<<1664, 256, 0, stream>>>(x, wq,bq,gq,betaq,mq,vq, wk,bk,gk,betak,mk,vk, qk_part);
  k_stageB<<<16, 256, 0, stream>>>(qk_part, wi,bi,gi,betai,mi,vi, gate);
  k_gateMul<<<2048, 256, 0, stream>>>(x, gate, (float*)d_out);
}

// Round 10
// 66.940 us; speedup vs baseline: 1.0679x; 1.0679x over previous
//
#include <hip/hip_runtime.h>
#include <cstdint>
#include <cstddef>

#define EPSV 1e-5f
typedef uint32_t u32;
typedef unsigned short u16;
typedef __attribute__((ext_vector_type(8))) short bf16x8;
typedef __attribute__((ext_vector_type(4))) float f32x4;

__device__ __forceinline__ u16 f2b(float x){ union { float f; u32 i; } v; v.f=x; u32 t=v.i; return (u16)((t + 0x7fffu + ((t>>16)&1u))>>16); }

// ---------------- prep: scale-fold W, convert bf16, store in MFMA B-frag order ----------------
// frag layout: idx = ((kk*4 + nt)*64 + lane)*8 + j  ->  c = kk*32 + (lane>>4)*8 + j, o = nt*16 + (lane&15)
__global__ __launch_bounds__(256) void k_prep(
    const float* __restrict__ wq, const float* __restrict__ bq, const float* __restrict__ gq,
    const float* __restrict__ betaq, const float* __restrict__ mq, const float* __restrict__ vq,
    const float* __restrict__ wk, const float* __restrict__ bk, const float* __restrict__ gk,
    const float* __restrict__ betak, const float* __restrict__ mk, const float* __restrict__ vk,
    u16* __restrict__ Wswz, float* __restrict__ D)
{
  const int idx = blockIdx.x*256 + threadIdx.x;   // 64 blocks x 256 = 16384
  const int j = idx & 7, lane = (idx >> 3) & 63, nt = (idx >> 9) & 3, kk = idx >> 11;
  const int c = kk*32 + ((lane >> 4) << 3) + j;
  const int o = nt*16 + (lane & 15);
  float w, g, v;
  if (o < 32) { w = wq[o*256 + c];      g = gq[o];    v = vq[o]; }
  else        { w = wk[(o-32)*256 + c]; g = gk[o-32]; v = vk[o-32]; }
  Wswz[idx] = f2b(w * (g * rsqrtf(v + EPSV)));
  if (idx < 64) {
    float gg,b,be,m,vv;
    if (idx < 32) { gg=gq[idx];    b=bq[idx];    be=betaq[idx];    m=mq[idx];    vv=vq[idx]; }
    else          { gg=gk[idx-32]; b=bk[idx-32]; be=betak[idx-32]; m=mk[idx-32]; vv=vk[idx-32]; }
    const float s = gg * rsqrtf(vv + EPSV);
    D[idx] = (b - m)*s + be;
  }
}

// ---------------- stage A (MFMA): conv1x1(q,k) + BN + ReLU + spatial partial-sum ----------------
// grid: 1664 blocks = 128 n x 13 tile-groups; 256 threads = 4 waves, wave = one 16-px tile.
// B-fragments read DIRECTLY from global Wswz (32KB, L2-resident, lane-contiguous 16B =
// perfectly coalesced). No W staging in LDS -> only a 1KB reduce buffer.
__global__ __launch_bounds__(256) void k_stageA(
    const float* __restrict__ x, const u16* __restrict__ Wswz, const float* __restrict__ D,
    float* __restrict__ qk_part)
{
  __shared__ float red[256];
  const int tid = threadIdx.x;
  const int n = blockIdx.x / 13, g = blockIdx.x % 13;
  const int wv = tid >> 6, lane = tid & 63;
  const int tile = g*4 + wv;
  const bool active = (tile < 49);

  float s4[4] = {0.f, 0.f, 0.f, 0.f};
  if (active) {
    const int px = tile*16 + (lane & 15);
    const float* xr = x + (size_t)n*200704 + px;
    const int krow = (lane >> 4) * 8;           // k-offset within the 32-wide K step
    const bf16x8* Wf = (const bf16x8*)Wswz;     // L2-resident fragments

    f32x4 acc[4];
#pragma unroll
    for (int nt = 0; nt < 4; ++nt) acc[nt] = (f32x4){0.f, 0.f, 0.f, 0.f};

    float a[8], an[8];
#pragma unroll
    for (int j = 0; j < 8; ++j) a[j] = xr[(size_t)(krow + j)*784];

#pragma unroll
    for (int kk = 0; kk < 8; ++kk) {
      if (kk < 7) {
#pragma unroll
        for (int j = 0; j < 8; ++j) an[j] = xr[(size_t)((kk+1)*32 + krow + j)*784];
      }
      bf16x8 af;
#pragma unroll
      for (int j = 0; j < 8; ++j) af[j] = (short)f2b(a[j]);
#pragma unroll
      for (int nt = 0; nt < 4; ++nt) {
        const bf16x8 bf = Wf[(kk*4 + nt)*64 + lane];
        acc[nt] = __builtin_amdgcn_mfma_f32_16x16x32_bf16(af, bf, acc[nt], 0, 0, 0);
      }
#pragma unroll
      for (int j = 0; j < 8; ++j) a[j] = an[j];
    }

    // epilogue: +D, ReLU, sum over the tile's 16 px
    // C layout: o = nt*16 + (lane&15), px-row = (lane>>4)*4 + r
#pragma unroll
    for (int nt = 0; nt < 4; ++nt) {
      const float d = D[nt*16 + (lane & 15)];
      float s = 0.f;
#pragma unroll
      for (int r = 0; r < 4; ++r) s += fmaxf(acc[nt][r] + d, 0.f);
      s += __shfl_down(s, 16, 64);
      s += __shfl_down(s, 32, 64);
      s4[nt] = s;                               // valid on lanes 0..15
    }
  }

  if (lane < 16) {
#pragma unroll
    for (int nt = 0; nt < 4; ++nt)
      red[wv*64 + nt*16 + lane] = active ? s4[nt] : 0.f;
  }
  __syncthreads();
  if (tid < 64) {
    qk_part[(size_t)(n*13 + g)*64 + tid] =
        red[tid] + red[64+tid] + red[128+tid] + red[192+tid];
  }
}

// ---------------- stage B: per-group 8x8 attention + conv_inflate + BN + ReLU + sigmoid ----------------
__global__ __launch_bounds__(256) void k_stageB(
    const float* __restrict__ qk_part,
    const float* __restrict__ wi, const float* __restrict__ bi, const float* __restrict__ gi,
    const float* __restrict__ betai, const float* __restrict__ mi, const float* __restrict__ vi,
    float* __restrict__ gate)
{
  __shared__ float ql[8][32], vl[8][32], attl[8][8], qul[8][32];
  const int tid = threadIdx.x;
  const int b = blockIdx.x;

  { // gather the 13 tile-group sums, convert to means
    const int i = tid >> 5, c = tid & 31;
    const int n = b*8 + i;
    float sq = 0.f, sv = 0.f;
#pragma unroll
    for (int qq = 0; qq < 13; ++qq) {
      sq += qk_part[(size_t)(n*13 + qq)*64 + c];
      sv += qk_part[(size_t)(n*13 + qq)*64 + 32 + c];
    }
    ql[i][c] = sq * (1.f/784.f);
    vl[i][c] = sv * (1.f/784.f);
  }
  __syncthreads();

  if (tid < 64) { // att[i][j] = -q_i.q_j ; softmax over i (axis 1) for fixed j
    const int i = tid >> 3, j = tid & 7;
    float d = 0.f;
#pragma unroll
    for (int c = 0; c < 32; ++c) d += ql[i][c]*ql[j][c];
    float a = -d;
    float m = a;                        // reduce over i: tid bits 3..5
    m = fmaxf(m, __shfl_xor(m, 8, 64));
    m = fmaxf(m, __shfl_xor(m, 16, 64));
    m = fmaxf(m, __shfl_xor(m, 32, 64));
    const float e = __expf(a - m);
    float s = e;
    s += __shfl_xor(s, 8, 64);
    s += __shfl_xor(s, 16, 64);
    s += __shfl_xor(s, 32, 64);
    attl[i][j] = e / s;
  }
  __syncthreads();

  { // q_upd[i][c] = sum_j att[i][j]*v[j][c] + v[i][c]
    const int i = tid >> 5, c = tid & 31;
    float acc = vl[i][c];
#pragma unroll
    for (int j = 0; j < 8; ++j) acc = fmaf(attl[i][j], vl[j][c], acc);
    qul[i][c] = acc;
  }
  __syncthreads();

  { // y[n,cout] = q_upd . wi[cout,:] (+bi), BN, ReLU, sigmoid
    const int cout = tid;
    float w[32];
#pragma unroll
    for (int k = 0; k < 32; ++k) w[k] = wi[cout*32 + k];
    const float s  = gi[cout] * rsqrtf(vi[cout] + EPSV);
    const float dd = (bi[cout] - mi[cout]) * s + betai[cout];
#pragma unroll
    for (int i = 0; i < 8; ++i) {
      float y = 0.f;
#pragma unroll
      for (int k = 0; k < 32; ++k) y = fmaf(qul[i][k], w[k], y);
      const float t = fmaxf(fmaf(y, s, dd), 0.f);
      gate[(size_t)(b*8 + i)*256 + cout] = 1.f / (1.f + __expf(-t));
    }
  }
}

// ---------------- stage C: out = gate[n,c] * x ----------------
__global__ __launch_bounds__(256) void k_gateMul(
    const float* __restrict__ x, const float* __restrict__ gate, float* __restrict__ out)
{
  const u32 nchunk = 128u*256u*196u;   // 6,422,528 float4 chunks; 196 per (n,c) row
  const u32 stride = gridDim.x * 256u;
  for (u32 q = blockIdx.x*256u + threadIdx.x; q < nchunk; q += stride) {
    const u32 cn = q / 196u;           // n*256 + c
    const float g = gate[cn];
    const float4 v = reinterpret_cast<const float4*>(x)[q];
    float4 o4;
    o4.x = v.x * g; o4.y = v.y * g; o4.z = v.z * g; o4.w = v.w * g;
    reinterpret_cast<float4*>(out)[q] = o4;
  }
}

extern "C" void kernel_launch(void* const* d_in, const int* in_sizes, int n_in,
                              void* d_out, int out_size, void* d_ws, size_t ws_size,
                              hipStream_t stream) {
  const float* x    = (const float*)d_in[0];
  const float* wq   = (const float*)d_in[1];
  const float* bq   = (const float*)d_in[2];
  const float* gq   = (const float*)d_in[3];
  const float* betaq= (const float*)d_in[4];
  const float* mq   = (const float*)d_in[5];
  const float* vq   = (const float*)d_in[6];
  const float* wk   = (const float*)d_in[7];
  const float* bk   = (const float*)d_in[8];
  const float* gk   = (const float*)d_in[9];
  const float* betak= (const float*)d_in[10];
  const float* mk   = (const float*)d_in[11];
  const float* vk   = (const float*)d_in[12];
  const float* wi   = (const float*)d_in[13];
  const float* bi   = (const float*)d_in[14];
  const float* gi   = (const float*)d_in[15];
  const float* betai= (const float*)d_in[16];
  const float* mi   = (const float*)d_in[17];
  const float* vi   = (const float*)d_in[18];

  char* ws = (char*)d_ws;
  float* qk_part = (float*)(ws);                     // 128*13*64*4 = 425984 B
  float* gate    = (float*)(ws + 425984);            // 128*256*4   = 131072 B
  u16*   Wswz    = (u16*)  (ws + 557056);            // 16384*2     =  32768 B
  float* Dc      = (float*)(ws + 589824);            // 64*4

  k_prep<<<64, 256, 0, stream>>>(wq,bq,gq,betaq,mq,vq, wk,bk,gk,betak,mk,vk, Wswz, Dc);
  k_stageA<<<1664, 256, 0, stream>>>(x, Wswz, Dc, qk_part);
  k_stageB<<<16, 256, 0, stream>>>(qk_part, wi,bi,gi,betai,mi,vi, gate);
  k_gateMul<<<2048, 256, 0, stream>>>(x, gate, (float*)d_out);
}

// Round 11
// 65.621 us; speedup vs baseline: 1.0894x; 1.0201x over previous
//
#include <hip/hip_runtime.h>
#include <cstdint>
#include <cstddef>

#define EPSV 1e-5f
typedef uint32_t u32;
typedef unsigned short u16;
typedef __attribute__((ext_vector_type(8))) short bf16x8;
typedef __attribute__((ext_vector_type(4))) float f32x4;

__device__ __forceinline__ u16 f2b(float x){ union { float f; u32 i; } v; v.f=x; u32 t=v.i; return (u16)((t + 0x7fffu + ((t>>16)&1u))>>16); }

// ---------------- prep: scale-fold W, convert bf16, store in MFMA B-frag order ----------------
// frag layout: idx = ((kk*4 + nt)*64 + lane)*8 + j  ->  c = kk*32 + (lane>>4)*8 + j, o = nt*16 + (lane&15)
__global__ __launch_bounds__(256) void k_prep(
    const float* __restrict__ wq, const float* __restrict__ bq, const float* __restrict__ gq,
    const float* __restrict__ betaq, const float* __restrict__ mq, const float* __restrict__ vq,
    const float* __restrict__ wk, const float* __restrict__ bk, const float* __restrict__ gk,
    const float* __restrict__ betak, const float* __restrict__ mk, const float* __restrict__ vk,
    u16* __restrict__ Wswz, float* __restrict__ D)
{
  const int idx = blockIdx.x*256 + threadIdx.x;   // 64 blocks x 256 = 16384
  const int j = idx & 7, lane = (idx >> 3) & 63, nt = (idx >> 9) & 3, kk = idx >> 11;
  const int c = kk*32 + ((lane >> 4) << 3) + j;
  const int o = nt*16 + (lane & 15);
  float w, g, v;
  if (o < 32) { w = wq[o*256 + c];      g = gq[o];    v = vq[o]; }
  else        { w = wk[(o-32)*256 + c]; g = gk[o-32]; v = vk[o-32]; }
  Wswz[idx] = f2b(w * (g * rsqrtf(v + EPSV)));
  if (idx < 64) {
    float gg,b,be,m,vv;
    if (idx < 32) { gg=gq[idx];    b=bq[idx];    be=betaq[idx];    m=mq[idx];    vv=vq[idx]; }
    else          { gg=gk[idx-32]; b=bk[idx-32]; be=betak[idx-32]; m=mk[idx-32]; vv=vk[idx-32]; }
    const float s = gg * rsqrtf(vv + EPSV);
    D[idx] = (b - m)*s + be;
  }
}

// ---------------- stage A (MFMA): conv1x1(q,k) + BN + ReLU + spatial partial-sum ----------------
// grid: 1664 blocks = 128 n x 13 tile-groups; 256 threads = 4 waves, wave = one 16-px tile.
// B-fragments read directly from global Wswz (32KB, L2-resident, lane-contiguous 16B).
__global__ __launch_bounds__(256) void k_stageA(
    const float* __restrict__ x, const u16* __restrict__ Wswz, const float* __restrict__ D,
    float* __restrict__ qk_part)
{
  __shared__ float red[256];
  const int tid = threadIdx.x;
  const int n = blockIdx.x / 13, g = blockIdx.x % 13;
  const int wv = tid >> 6, lane = tid & 63;
  const int tile = g*4 + wv;
  const bool active = (tile < 49);

  float s4[4] = {0.f, 0.f, 0.f, 0.f};
  if (active) {
    const int px = tile*16 + (lane & 15);
    const float* xr = x + (size_t)n*200704 + px;
    const int krow = (lane >> 4) * 8;           // k-offset within the 32-wide K step
    const bf16x8* Wf = (const bf16x8*)Wswz;     // L2-resident fragments

    f32x4 acc[4];
#pragma unroll
    for (int nt = 0; nt < 4; ++nt) acc[nt] = (f32x4){0.f, 0.f, 0.f, 0.f};

    float a[8], an[8];
#pragma unroll
    for (int j = 0; j < 8; ++j) a[j] = xr[(size_t)(krow + j)*784];

#pragma unroll
    for (int kk = 0; kk < 8; ++kk) {
      if (kk < 7) {
#pragma unroll
        for (int j = 0; j < 8; ++j) an[j] = xr[(size_t)((kk+1)*32 + krow + j)*784];
      }
      bf16x8 af;
#pragma unroll
      for (int j = 0; j < 8; ++j) af[j] = (short)f2b(a[j]);
#pragma unroll
      for (int nt = 0; nt < 4; ++nt) {
        const bf16x8 bf = Wf[(kk*4 + nt)*64 + lane];
        acc[nt] = __builtin_amdgcn_mfma_f32_16x16x32_bf16(af, bf, acc[nt], 0, 0, 0);
      }
#pragma unroll
      for (int j = 0; j < 8; ++j) a[j] = an[j];
    }

    // epilogue: +D, ReLU, sum over the tile's 16 px
    // C layout: o = nt*16 + (lane&15), px-row = (lane>>4)*4 + r
#pragma unroll
    for (int nt = 0; nt < 4; ++nt) {
      const float d = D[nt*16 + (lane & 15)];
      float s = 0.f;
#pragma unroll
      for (int r = 0; r < 4; ++r) s += fmaxf(acc[nt][r] + d, 0.f);
      s += __shfl_down(s, 16, 64);
      s += __shfl_down(s, 32, 64);
      s4[nt] = s;                               // valid on lanes 0..15
    }
  }

  if (lane < 16) {
#pragma unroll
    for (int nt = 0; nt < 4; ++nt)
      red[wv*64 + nt*16 + lane] = active ? s4[nt] : 0.f;
  }
  __syncthreads();
  if (tid < 64) {
    qk_part[(size_t)(n*13 + g)*64 + tid] =
        red[tid] + red[64+tid] + red[128+tid] + red[192+tid];
  }
}

// ---------------- fused stage B + C: per-block attention slice + gate + streaming multiply ----
// grid: 2048 blocks; block blk covers n = blk>>4, couts c0 = (blk&15)*16 .. +16,
// i.e. 16 (n,c) rows x 196 float4 chunks = 3136 chunks.
__global__ __launch_bounds__(256) void k_gateMulB(
    const float* __restrict__ x, const float* __restrict__ qk_part,
    const float* __restrict__ wi, const float* __restrict__ bi, const float* __restrict__ gi,
    const float* __restrict__ betai, const float* __restrict__ mi, const float* __restrict__ vi,
    float* __restrict__ out)
{
  __shared__ float ql[8][32], vl[8][32], attl[8][8], gl[16];
  const int tid = threadIdx.x;
  const int blk = blockIdx.x;
  const int n  = blk >> 4;             // image index
  const int c0 = (blk & 15) << 4;      // first cout of this block
  const int b  = n >> 3, i0 = n & 7;   // segment group, row within group

  { // gather the group's q/v means (13 partials each) -- qk_part is L2-resident
    const int i = tid >> 5, c = tid & 31;
    const int nn = b*8 + i;
    float sq = 0.f, sv = 0.f;
#pragma unroll
    for (int qq = 0; qq < 13; ++qq) {
      sq += qk_part[(size_t)(nn*13 + qq)*64 + c];
      sv += qk_part[(size_t)(nn*13 + qq)*64 + 32 + c];
    }
    ql[i][c] = sq * (1.f/784.f);
    vl[i][c] = sv * (1.f/784.f);
  }
  __syncthreads();

  if (tid < 64) { // att[i][j] = -q_i.q_j ; softmax over i (axis 1) for fixed j
    const int i = tid >> 3, j = tid & 7;
    float d = 0.f;
#pragma unroll
    for (int c = 0; c < 32; ++c) d += ql[i][c]*ql[j][c];
    float a = -d;
    float m = a;                        // reduce over i: tid bits 3..5
    m = fmaxf(m, __shfl_xor(m, 8, 64));
    m = fmaxf(m, __shfl_xor(m, 16, 64));
    m = fmaxf(m, __shfl_xor(m, 32, 64));
    const float e = __expf(a - m);
    float s = e;
    s += __shfl_xor(s, 8, 64);
    s += __shfl_xor(s, 16, 64);
    s += __shfl_xor(s, 32, 64);
    attl[i][j] = e / s;
  }
  __syncthreads();

  if (tid < 16) { // gate for cout = c0+tid, row i0: q_upd[i0]·wi[cout,:] + BN + ReLU + sigmoid
    const int cout = c0 + tid;
    const float s  = gi[cout] * rsqrtf(vi[cout] + EPSV);
    const float dd = (bi[cout] - mi[cout]) * s + betai[cout];
    float y = 0.f;
#pragma unroll
    for (int k = 0; k < 32; ++k) {
      float qu = vl[i0][k];
#pragma unroll
      for (int j = 0; j < 8; ++j) qu = fmaf(attl[i0][j], vl[j][k], qu);
      y = fmaf(qu, wi[cout*32 + k], y);
    }
    const float t = fmaxf(fmaf(y, s, dd), 0.f);
    gl[tid] = 1.f / (1.f + __expf(-t));
  }
  __syncthreads();

  // streaming multiply: 16 rows x 196 chunks
  const float4* xb = reinterpret_cast<const float4*>(x)   + (size_t)(n*256 + c0)*196;
  float4*       ob = reinterpret_cast<float4*>(out)       + (size_t)(n*256 + c0)*196;
#pragma unroll 4
  for (int q = tid; q < 3136; q += 256) {
    const int row = q / 196;           // 0..15
    const float g = gl[row];
    const float4 v = xb[q];
    float4 o4;
    o4.x = v.x * g; o4.y = v.y * g; o4.z = v.z * g; o4.w = v.w * g;
    ob[q] = o4;
  }
}

extern "C" void kernel_launch(void* const* d_in, const int* in_sizes, int n_in,
                              void* d_out, int out_size, void* d_ws, size_t ws_size,
                              hipStream_t stream) {
  const float* x    = (const float*)d_in[0];
  const float* wq   = (const float*)d_in[1];
  const float* bq   = (const float*)d_in[2];
  const float* gq   = (const float*)d_in[3];
  const float* betaq= (const float*)d_in[4];
  const float* mq   = (const float*)d_in[5];
  const float* vq   = (const float*)d_in[6];
  const float* wk   = (const float*)d_in[7];
  const float* bk   = (const float*)d_in[8];
  const float* gk   = (const float*)d_in[9];
  const float* betak= (const float*)d_in[10];
  const float* mk   = (const float*)d_in[11];
  const float* vk   = (const float*)d_in[12];
  const float* wi   = (const float*)d_in[13];
  const float* bi   = (const float*)d_in[14];
  const float* gi   = (const float*)d_in[15];
  const float* betai= (const float*)d_in[16];
  const float* mi   = (const float*)d_in[17];
  const float* vi   = (const float*)d_in[18];

  char* ws = (char*)d_ws;
  float* qk_part = (float*)(ws);                     // 128*13*64*4 = 425984 B
  u16*   Wswz    = (u16*)  (ws + 425984);            // 16384*2     =  32768 B
  float* Dc      = (float*)(ws + 458752);            // 64*4

  k_prep<<<64, 256, 0, stream>>>(wq,bq,gq,betaq,mq,vq, wk,bk,gk,betak,mk,vk, Wswz, Dc);
  k_stageA<<<1664, 256, 0, stream>>>(x, Wswz, Dc, qk_part);
  k_gateMulB<<<2048, 256, 0, stream>>>(x, qk_part, wi,bi,gi,betai,mi,vi, (float*)d_out);
}

// Round 14
// 65.466 us; speedup vs baseline: 1.0920x; 1.0024x over previous
//
#include <hip/hip_runtime.h>
#include <cstdint>
#include <cstddef>

#define EPSV 1e-5f
typedef uint32_t u32;
typedef unsigned short u16;
typedef __attribute__((ext_vector_type(8))) short bf16x8;
typedef __attribute__((ext_vector_type(4))) float f32x4;

__device__ __forceinline__ u16 f2b(float x){ union { float f; u32 i; } v; v.f=x; u32 t=v.i; return (u16)((t + 0x7fffu + ((t>>16)&1u))>>16); }

// ---------------- prep: scale-fold W, convert bf16, store in MFMA B-frag order ----------------
// frag layout: idx = ((kk*4 + nt)*64 + lane)*8 + j  ->  c = kk*32 + (lane>>4)*8 + j, o = nt*16 + (lane&15)
__global__ __launch_bounds__(256) void k_prep(
    const float* __restrict__ wq, const float* __restrict__ bq, const float* __restrict__ gq,
    const float* __restrict__ betaq, const float* __restrict__ mq, const float* __restrict__ vq,
    const float* __restrict__ wk, const float* __restrict__ bk, const float* __restrict__ gk,
    const float* __restrict__ betak, const float* __restrict__ mk, const float* __restrict__ vk,
    u16* __restrict__ Wswz, float* __restrict__ D)
{
  const int idx = blockIdx.x*256 + threadIdx.x;   // 64 blocks x 256 = 16384
  const int j = idx & 7, lane = (idx >> 3) & 63, nt = (idx >> 9) & 3, kk = idx >> 11;
  const int c = kk*32 + ((lane >> 4) << 3) + j;
  const int o = nt*16 + (lane & 15);
  float w, g, v;
  if (o < 32) { w = wq[o*256 + c];      g = gq[o];    v = vq[o]; }
  else        { w = wk[(o-32)*256 + c]; g = gk[o-32]; v = vk[o-32]; }
  Wswz[idx] = f2b(w * (g * rsqrtf(v + EPSV)));
  if (idx < 64) {
    float gg,b,be,m,vv;
    if (idx < 32) { gg=gq[idx];    b=bq[idx];    be=betaq[idx];    m=mq[idx];    vv=vq[idx]; }
    else          { gg=gk[idx-32]; b=bk[idx-32]; be=betak[idx-32]; m=mk[idx-32]; vv=vk[idx-32]; }
    const float s = gg * rsqrtf(vv + EPSV);
    D[idx] = (b - m)*s + be;
  }
}

// ---------------- stage A (MFMA): conv1x1(q,k) + BN + ReLU + spatial partial-sum ----------------
// grid: 1664 blocks = 128 n x 13 tile-groups; 256 threads = 4 waves, wave = one 16-px tile.
// B-fragments read directly from global Wswz (32KB, L2-resident, lane-contiguous 16B).
__global__ __launch_bounds__(256) void k_stageA(
    const float* __restrict__ x, const u16* __restrict__ Wswz, const float* __restrict__ D,
    float* __restrict__ qk_part)
{
  __shared__ float red[256];
  const int tid = threadIdx.x;
  const int n = blockIdx.x / 13, g = blockIdx.x % 13;
  const int wv = tid >> 6, lane = tid & 63;
  const int tile = g*4 + wv;
  const bool active = (tile < 49);

  float s4[4] = {0.f, 0.f, 0.f, 0.f};
  if (active) {
    const int px = tile*16 + (lane & 15);
    const float* xr = x + (size_t)n*200704 + px;
    const int krow = (lane >> 4) * 8;           // k-offset within the 32-wide K step
    const bf16x8* Wf = (const bf16x8*)Wswz;     // L2-resident fragments

    f32x4 acc[4];
#pragma unroll
    for (int nt = 0; nt < 4; ++nt) acc[nt] = (f32x4){0.f, 0.f, 0.f, 0.f};

    float a[8], an[8];
#pragma unroll
    for (int j = 0; j < 8; ++j) a[j] = xr[(size_t)(krow + j)*784];

#pragma unroll
    for (int kk = 0; kk < 8; ++kk) {
      if (kk < 7) {
#pragma unroll
        for (int j = 0; j < 8; ++j) an[j] = xr[(size_t)((kk+1)*32 + krow + j)*784];
      }
      bf16x8 af;
#pragma unroll
      for (int j = 0; j < 8; ++j) af[j] = (short)f2b(a[j]);
#pragma unroll
      for (int nt = 0; nt < 4; ++nt) {
        const bf16x8 bf = Wf[(kk*4 + nt)*64 + lane];
        acc[nt] = __builtin_amdgcn_mfma_f32_16x16x32_bf16(af, bf, acc[nt], 0, 0, 0);
      }
#pragma unroll
      for (int j = 0; j < 8; ++j) a[j] = an[j];
    }

    // epilogue: +D, ReLU, sum over the tile's 16 px
    // C layout: o = nt*16 + (lane&15), px-row = (lane>>4)*4 + r
#pragma unroll
    for (int nt = 0; nt < 4; ++nt) {
      const float d = D[nt*16 + (lane & 15)];
      float s = 0.f;
#pragma unroll
      for (int r = 0; r < 4; ++r) s += fmaxf(acc[nt][r] + d, 0.f);
      s += __shfl_down(s, 16, 64);
      s += __shfl_down(s, 32, 64);
      s4[nt] = s;                               // valid on lanes 0..15
    }
  }

  if (lane < 16) {
#pragma unroll
    for (int nt = 0; nt < 4; ++nt)
      red[wv*64 + nt*16 + lane] = active ? s4[nt] : 0.f;
  }
  __syncthreads();
  if (tid < 64) {
    qk_part[(size_t)(n*13 + g)*64 + tid] =
        red[tid] + red[64+tid] + red[128+tid] + red[192+tid];
  }
}

// ---------------- fused stage B + C: per-block attention slice + gate + streaming multiply ----
// grid: 2048 blocks; block blk covers n = blk>>4, couts c0 = (blk&15)*16 .. +16,
// i.e. 16 (n,c) rows x 196 f32x4 chunks = 3136 chunks.
__global__ __launch_bounds__(256) void k_gateMulB(
    const float* __restrict__ x, const float* __restrict__ qk_part,
    const float* __restrict__ wi, const float* __restrict__ bi, const float* __restrict__ gi,
    const float* __restrict__ betai, const float* __restrict__ mi, const float* __restrict__ vi,
    float* __restrict__ out)
{
  __shared__ float ql[8][32], vl[8][32], attl[8][8], gl[16];
  const int tid = threadIdx.x;
  const int blk = blockIdx.x;
  const int n  = blk >> 4;             // image index
  const int c0 = (blk & 15) << 4;      // first cout of this block
  const int b  = n >> 3, i0 = n & 7;   // segment group, row within group

  { // gather the group's q/v means (13 partials each) -- qk_part is L2-resident
    const int i = tid >> 5, c = tid & 31;
    const int nn = b*8 + i;
    float sq = 0.f, sv = 0.f;
#pragma unroll
    for (int qq = 0; qq < 13; ++qq) {
      sq += qk_part[(size_t)(nn*13 + qq)*64 + c];
      sv += qk_part[(size_t)(nn*13 + qq)*64 + 32 + c];
    }
    ql[i][c] = sq * (1.f/784.f);
    vl[i][c] = sv * (1.f/784.f);
  }
  __syncthreads();

  if (tid < 64) { // att[i][j] = -q_i.q_j ; softmax over i (axis 1) for fixed j
    const int i = tid >> 3, j = tid & 7;
    float d = 0.f;
#pragma unroll
    for (int c = 0; c < 32; ++c) d += ql[i][c]*ql[j][c];
    float a = -d;
    float m = a;                        // reduce over i: tid bits 3..5
    m = fmaxf(m, __shfl_xor(m, 8, 64));
    m = fmaxf(m, __shfl_xor(m, 16, 64));
    m = fmaxf(m, __shfl_xor(m, 32, 64));
    const float e = __expf(a - m);
    float s = e;
    s += __shfl_xor(s, 8, 64);
    s += __shfl_xor(s, 16, 64);
    s += __shfl_xor(s, 32, 64);
    attl[i][j] = e / s;
  }
  __syncthreads();

  if (tid < 16) { // gate for cout = c0+tid, row i0: q_upd[i0]·wi[cout,:] + BN + ReLU + sigmoid
    const int cout = c0 + tid;
    const float s  = gi[cout] * rsqrtf(vi[cout] + EPSV);
    const float dd = (bi[cout] - mi[cout]) * s + betai[cout];
    float y = 0.f;
#pragma unroll
    for (int k = 0; k < 32; ++k) {
      float qu = vl[i0][k];
#pragma unroll
      for (int j = 0; j < 8; ++j) qu = fmaf(attl[i0][j], vl[j][k], qu);
      y = fmaf(qu, wi[cout*32 + k], y);
    }
    const float t = fmaxf(fmaf(y, s, dd), 0.f);
    gl[tid] = 1.f / (1.f + __expf(-t));
  }
  __syncthreads();

  // streaming multiply: 16 rows x 196 chunks; out is write-once -> non-temporal stores
  const f32x4* xb = reinterpret_cast<const f32x4*>(x)   + (size_t)(n*256 + c0)*196;
  f32x4*       ob = reinterpret_cast<f32x4*>(out)       + (size_t)(n*256 + c0)*196;
#pragma unroll 4
  for (int q = tid; q < 3136; q += 256) {
    const int row = q / 196;           // 0..15
    const float g = gl[row];
    const f32x4 v = xb[q];
    const f32x4 o4 = v * g;
    __builtin_nontemporal_store(o4, ob + q);
  }
}

extern "C" void kernel_launch(void* const* d_in, const int* in_sizes, int n_in,
                              void* d_out, int out_size, void* d_ws, size_t ws_size,
                              hipStream_t stream) {
  const float* x    = (const float*)d_in[0];
  const float* wq   = (const float*)d_in[1];
  const float* bq   = (const float*)d_in[2];
  const float* gq   = (const float*)d_in[3];
  const float* betaq= (const float*)d_in[4];
  const float* mq   = (const float*)d_in[5];
  const float* vq   = (const float*)d_in[6];
  const float* wk   = (const float*)d_in[7];
  const float* bk   = (const float*)d_in[8];
  const float* gk   = (const float*)d_in[9];
  const float* betak= (const float*)d_in[10];
  const float* mk   = (const float*)d_in[11];
  const float* vk   = (const float*)d_in[12];
  const float* wi   = (const float*)d_in[13];
  const float* bi   = (const float*)d_in[14];
  const float* gi   = (const float*)d_in[15];
  const float* betai= (const float*)d_in[16];
  const float* mi   = (const float*)d_in[17];
  const float* vi   = (const float*)d_in[18];

  char* ws = (char*)d_ws;
  float* qk_part = (float*)(ws);                     // 128*13*64*4 = 425984 B
  u16*   Wswz    = (u16*)  (ws + 425984);            // 16384*2     =  32768 B
  float* Dc      = (float*)(ws + 458752);            // 64*4

  k_prep<<<64, 256, 0, stream>>>(wq,bq,gq,betaq,mq,vq, wk,bk,gk,betak,mk,vk, Wswz, Dc);
  k_stageA<<<1664, 256, 0, stream>>>(x, Wswz, Dc, qk_part);
  k_gateMulB<<<2048, 256, 0, stream>>>(x, qk_part, wi,bi,gi,betai,mi,vi, (float*)d_out);
}

// Round 15
// 65.185 us; speedup vs baseline: 1.0967x; 1.0043x over previous
//
#include <hip/hip_runtime.h>
#include <cstdint>
#include <cstddef>

#define EPSV 1e-5f
typedef uint32_t u32;
typedef unsigned short u16;
typedef __attribute__((ext_vector_type(8))) short bf16x8;
typedef __attribute__((ext_vector_type(4))) float f32x4;

__device__ __forceinline__ u16 f2b(float x){ union { float f; u32 i; } v; v.f=x; u32 t=v.i; return (u16)((t + 0x7fffu + ((t>>16)&1u))>>16); }

// ---------------- prep: scale-fold W, convert bf16, store in MFMA B-frag order ----------------
// frag layout: idx = ((kk*4 + nt)*64 + lane)*8 + j  ->  c = kk*32 + (lane>>4)*8 + j, o = nt*16 + (lane&15)
__global__ __launch_bounds__(256) void k_prep(
    const float* __restrict__ wq, const float* __restrict__ bq, const float* __restrict__ gq,
    const float* __restrict__ betaq, const float* __restrict__ mq, const float* __restrict__ vq,
    const float* __restrict__ wk, const float* __restrict__ bk, const float* __restrict__ gk,
    const float* __restrict__ betak, const float* __restrict__ mk, const float* __restrict__ vk,
    u16* __restrict__ Wswz, float* __restrict__ D)
{
  const int idx = blockIdx.x*256 + threadIdx.x;   // 64 blocks x 256 = 16384
  const int j = idx & 7, lane = (idx >> 3) & 63, nt = (idx >> 9) & 3, kk = idx >> 11;
  const int c = kk*32 + ((lane >> 4) << 3) + j;
  const int o = nt*16 + (lane & 15);
  float w, g, v;
  if (o < 32) { w = wq[o*256 + c];      g = gq[o];    v = vq[o]; }
  else        { w = wk[(o-32)*256 + c]; g = gk[o-32]; v = vk[o-32]; }
  Wswz[idx] = f2b(w * (g * rsqrtf(v + EPSV)));
  if (idx < 64) {
    float gg,b,be,m,vv;
    if (idx < 32) { gg=gq[idx];    b=bq[idx];    be=betaq[idx];    m=mq[idx];    vv=vq[idx]; }
    else          { gg=gk[idx-32]; b=bk[idx-32]; be=betak[idx-32]; m=mk[idx-32]; vv=vk[idx-32]; }
    const float s = gg * rsqrtf(vv + EPSV);
    D[idx] = (b - m)*s + be;
  }
}

// ---------------- stage A (MFMA): conv1x1(q,k) + BN + ReLU + spatial partial-sum ----------------
// grid: 1664 blocks = 128 n x 13 tile-groups; 256 threads = 4 waves, wave = one 16-px tile.
// B-fragments read directly from global Wswz (32KB, L2-resident, lane-contiguous 16B).
// x loads pipelined 2 kk-steps deep (16 outstanding/wave) to cover HBM/L3 latency.
__global__ __launch_bounds__(256) void k_stageA(
    const float* __restrict__ x, const u16* __restrict__ Wswz, const float* __restrict__ D,
    float* __restrict__ qk_part)
{
  __shared__ float red[256];
  const int tid = threadIdx.x;
  const int n = blockIdx.x / 13, g = blockIdx.x % 13;
  const int wv = tid >> 6, lane = tid & 63;
  const int tile = g*4 + wv;
  const bool active = (tile < 49);

  float s4[4] = {0.f, 0.f, 0.f, 0.f};
  if (active) {
    const int px = tile*16 + (lane & 15);
    const float* xr = x + (size_t)n*200704 + px;
    const int krow = (lane >> 4) * 8;           // k-offset within the 32-wide K step
    const bf16x8* Wf = (const bf16x8*)Wswz;     // L2-resident fragments

    f32x4 acc[4];
#pragma unroll
    for (int nt = 0; nt < 4; ++nt) acc[nt] = (f32x4){0.f, 0.f, 0.f, 0.f};

    float a0[8], a1[8], an[8];
#pragma unroll
    for (int j = 0; j < 8; ++j) a0[j] = xr[(size_t)(krow + j)*784];
#pragma unroll
    for (int j = 0; j < 8; ++j) a1[j] = xr[(size_t)(32 + krow + j)*784];

#pragma unroll
    for (int kk = 0; kk < 8; ++kk) {
      if (kk < 6) {
#pragma unroll
        for (int j = 0; j < 8; ++j) an[j] = xr[(size_t)((kk+2)*32 + krow + j)*784];
      }
      bf16x8 af;
#pragma unroll
      for (int j = 0; j < 8; ++j) af[j] = (short)f2b(a0[j]);
#pragma unroll
      for (int nt = 0; nt < 4; ++nt) {
        const bf16x8 bf = Wf[(kk*4 + nt)*64 + lane];
        acc[nt] = __builtin_amdgcn_mfma_f32_16x16x32_bf16(af, bf, acc[nt], 0, 0, 0);
      }
#pragma unroll
      for (int j = 0; j < 8; ++j) { a0[j] = a1[j]; a1[j] = an[j]; }
    }

    // epilogue: +D, ReLU, sum over the tile's 16 px
    // C layout: o = nt*16 + (lane&15), px-row = (lane>>4)*4 + r
#pragma unroll
    for (int nt = 0; nt < 4; ++nt) {
      const float d = D[nt*16 + (lane & 15)];
      float s = 0.f;
#pragma unroll
      for (int r = 0; r < 4; ++r) s += fmaxf(acc[nt][r] + d, 0.f);
      s += __shfl_down(s, 16, 64);
      s += __shfl_down(s, 32, 64);
      s4[nt] = s;                               // valid on lanes 0..15
    }
  }

  if (lane < 16) {
#pragma unroll
    for (int nt = 0; nt < 4; ++nt)
      red[wv*64 + nt*16 + lane] = active ? s4[nt] : 0.f;
  }
  __syncthreads();
  if (tid < 64) {
    qk_part[(size_t)(n*13 + g)*64 + tid] =
        red[tid] + red[64+tid] + red[128+tid] + red[192+tid];
  }
}

// ---------------- fused stage B + C: per-block attention slice + gate + streaming multiply ----
// grid: 2048 blocks; block blk covers n = blk>>4, couts c0 = (blk&15)*16 .. +16,
// i.e. 16 (n,c) rows x 196 f32x4 chunks = 3136 chunks.
__global__ __launch_bounds__(256) void k_gateMulB(
    const float* __restrict__ x, const float* __restrict__ qk_part,
    const float* __restrict__ wi, const float* __restrict__ bi, const float* __restrict__ gi,
    const float* __restrict__ betai, const float* __restrict__ mi, const float* __restrict__ vi,
    float* __restrict__ out)
{
  __shared__ float ql[8][32], vl[8][32], attl[8][8], gl[16];
  const int tid = threadIdx.x;
  const int blk = blockIdx.x;
  const int n  = blk >> 4;             // image index
  const int c0 = (blk & 15) << 4;      // first cout of this block
  const int b  = n >> 3, i0 = n & 7;   // segment group, row within group

  { // gather the group's q/v means (13 partials each) -- qk_part is L2-resident
    const int i = tid >> 5, c = tid & 31;
    const int nn = b*8 + i;
    float sq = 0.f, sv = 0.f;
#pragma unroll
    for (int qq = 0; qq < 13; ++qq) {
      sq += qk_part[(size_t)(nn*13 + qq)*64 + c];
      sv += qk_part[(size_t)(nn*13 + qq)*64 + 32 + c];
    }
    ql[i][c] = sq * (1.f/784.f);
    vl[i][c] = sv * (1.f/784.f);
  }
  __syncthreads();

  if (tid < 64) { // att[i][j] = -q_i.q_j ; softmax over i (axis 1) for fixed j
    const int i = tid >> 3, j = tid & 7;
    float d = 0.f;
#pragma unroll
    for (int c = 0; c < 32; ++c) d += ql[i][c]*ql[j][c];
    float a = -d;
    float m = a;                        // reduce over i: tid bits 3..5
    m = fmaxf(m, __shfl_xor(m, 8, 64));
    m = fmaxf(m, __shfl_xor(m, 16, 64));
    m = fmaxf(m, __shfl_xor(m, 32, 64));
    const float e = __expf(a - m);
    float s = e;
    s += __shfl_xor(s, 8, 64);
    s += __shfl_xor(s, 16, 64);
    s += __shfl_xor(s, 32, 64);
    attl[i][j] = e / s;
  }
  __syncthreads();

  if (tid < 16) { // gate for cout = c0+tid, row i0: q_upd[i0]·wi[cout,:] + BN + ReLU + sigmoid
    const int cout = c0 + tid;
    const float s  = gi[cout] * rsqrtf(vi[cout] + EPSV);
    const float dd = (bi[cout] - mi[cout]) * s + betai[cout];
    float y = 0.f;
#pragma unroll
    for (int k = 0; k < 32; ++k) {
      float qu = vl[i0][k];
#pragma unroll
      for (int j = 0; j < 8; ++j) qu = fmaf(attl[i0][j], vl[j][k], qu);
      y = fmaf(qu, wi[cout*32 + k], y);
    }
    const float t = fmaxf(fmaf(y, s, dd), 0.f);
    gl[tid] = 1.f / (1.f + __expf(-t));
  }
  __syncthreads();

  // streaming multiply: 16 rows x 196 chunks; out is write-once -> non-temporal stores
  const f32x4* xb = reinterpret_cast<const f32x4*>(x)   + (size_t)(n*256 + c0)*196;
  f32x4*       ob = reinterpret_cast<f32x4*>(out)       + (size_t)(n*256 + c0)*196;
#pragma unroll 4
  for (int q = tid; q < 3136; q += 256) {
    const int row = q / 196;           // 0..15
    const float g = gl[row];
    const f32x4 v = xb[q];
    const f32x4 o4 = v * g;
    __builtin_nontemporal_store(o4, ob + q);
  }
}

extern "C" void kernel_launch(void* const* d_in, const int* in_sizes, int n_in,
                              void* d_out, int out_size, void* d_ws, size_t ws_size,
                              hipStream_t stream) {
  const float* x    = (const float*)d_in[0];
  const float* wq   = (const float*)d_in[1];
  const float* bq   = (const float*)d_in[2];
  const float* gq   = (const float*)d_in[3];
  const float* betaq= (const float*)d_in[4];
  const float* mq   = (const float*)d_in[5];
  const float* vq   = (const float*)d_in[6];
  const float* wk   = (const float*)d_in[7];
  const float* bk   = (const float*)d_in[8];
  const float* gk   = (const float*)d_in[9];
  const float* betak= (const float*)d_in[10];
  const float* mk   = (const float*)d_in[11];
  const float* vk   = (const float*)d_in[12];
  const float* wi   = (const float*)d_in[13];
  const float* bi   = (const float*)d_in[14];
  const float* gi   = (const float*)d_in[15];
  const float* betai= (const float*)d_in[16];
  const float* mi   = (const float*)d_in[17];
  const float* vi   = (const float*)d_in[18];

  char* ws = (char*)d_ws;
  float* qk_part = (float*)(ws);                     // 128*13*64*4 = 425984 B
  u16*   Wswz    = (u16*)  (ws + 425984);            // 16384*2     =  32768 B
  float* Dc      = (float*)(ws + 458752);            // 64*4

  k_prep<<<64, 256, 0, stream>>>(wq,bq,gq,betaq,mq,vq, wk,bk,gk,betak,mk,vk, Wswz, Dc);
  k_stageA<<<1664, 256, 0, stream>>>(x, Wswz, Dc, qk_part);
  k_gateMulB<<<2048, 256, 0, stream>>>(x, qk_part, wi,bi,gi,betai,mi,vi, (float*)d_out);
}